// Round 1
// baseline (181.502 us; speedup 1.0000x reference)
//
#include <hip/hip_runtime.h>

#define NH 16
#define DH 64
#define SEQ 512
#define SIN 64
#define NBATCH 8

typedef short bf16x8 __attribute__((ext_vector_type(8)));
typedef float f32x4 __attribute__((ext_vector_type(4)));

__device__ __forceinline__ unsigned short f2bf(float f) {
  union { float f; unsigned u; } v; v.f = f;
  unsigned r = v.u + 0x7FFFu + ((v.u >> 16) & 1u);
  return (unsigned short)(r >> 16);
}
__device__ __forceinline__ float bf2f(unsigned short b) {
  union { unsigned u; float f; } v; v.u = ((unsigned)b) << 16;
  return v.f;
}
__device__ __forceinline__ f32x4 mfma16(bf16x8 a, bf16x8 b, f32x4 c) {
  return __builtin_amdgcn_mfma_f32_16x16x32_bf16(a, b, c, 0, 0, 0);
}
__device__ __forceinline__ void gload_lds16(const unsigned short* g, unsigned short* l) {
  __builtin_amdgcn_global_load_lds((const __attribute__((address_space(1))) void*)g,
                                   (__attribute__((address_space(3))) void*)l, 16, 0, 0);
}

// ---------------- convert kernels ----------------

__global__ __launch_bounds__(256) void k_convert_x(const float* __restrict__ hs,
                                                   const float* __restrict__ ihs,
                                                   unsigned short* __restrict__ X) {
  int idx = blockIdx.x * 256 + threadIdx.x;   // one float4 per thread; 4608*256 total
  float4 v;
  if (idx < 1048576) v = ((const float4*)hs)[idx];
  else               v = ((const float4*)ihs)[idx - 1048576];
  ushort4 o; o.x = f2bf(v.x); o.y = f2bf(v.y); o.z = f2bf(v.z); o.w = f2bf(v.w);
  ((ushort4*)X)[idx] = o;
}

__global__ __launch_bounds__(256) void k_convert_e(const float* __restrict__ de,
                                                   unsigned short* __restrict__ E) {
  int idx = blockIdx.x * 256 + threadIdx.x;   // one 4-elem chunk; 16384 total (1024*64/4)
  ushort4 o;
  if (idx < 16368) {                           // 1023*64/4 valid
    float4 v = ((const float4*)de)[idx];
    o.x = f2bf(v.x); o.y = f2bf(v.y); o.z = f2bf(v.z); o.w = f2bf(v.w);
  } else { o.x = 0; o.y = 0; o.z = 0; o.w = 0; }
  ((ushort4*)E)[idx] = o;
}

// transpose+convert W: Wt[(mat*1024 + n)*1024 + k] = W_mat[k*1024 + n], bf16
__global__ __launch_bounds__(256) void k_convert_w(const float* __restrict__ Wq,
                                                   const float* __restrict__ Wk,
                                                   const float* __restrict__ Wv,
                                                   unsigned short* __restrict__ Wt) {
  __shared__ float t[64][65];
  const float* W = (blockIdx.z == 0) ? Wq : (blockIdx.z == 1) ? Wk : Wv;
  const int n0 = blockIdx.x * 64, k0 = blockIdx.y * 64;
  const int tid = threadIdx.x;
  #pragma unroll
  for (int q = 0; q < 4; ++q) {
    int s = q * 256 + tid;
    int r = s >> 4, c4 = s & 15;
    float4 v = *(const float4*)(W + (size_t)(k0 + r) * 1024 + n0 + c4 * 4);
    t[r][c4 * 4 + 0] = v.x; t[r][c4 * 4 + 1] = v.y;
    t[r][c4 * 4 + 2] = v.z; t[r][c4 * 4 + 3] = v.w;
  }
  __syncthreads();
  #pragma unroll
  for (int q = 0; q < 4; ++q) {
    int s = q * 256 + tid;
    int rn = s >> 4, c4 = s & 15;
    ushort4 o;
    o.x = f2bf(t[c4 * 4 + 0][rn]); o.y = f2bf(t[c4 * 4 + 1][rn]);
    o.z = f2bf(t[c4 * 4 + 2][rn]); o.w = f2bf(t[c4 * 4 + 3][rn]);
    *(ushort4*)(Wt + ((size_t)(blockIdx.z << 10) + n0 + rn) * 1024 + k0 + c4 * 4) = o;
  }
}

// ---------------- fused QKV GEMM (m97-style 128x128, BK=32) ----------------
// C[4608,3072] = X @ Wt^T ; epilogue routes to Q,K,Vt(ransposed),IK,IVt with bias.
__global__ __launch_bounds__(256) void k_gemm(const unsigned short* __restrict__ X,
                                              const unsigned short* __restrict__ Wt,
                                              const float* __restrict__ bq,
                                              const float* __restrict__ bk,
                                              const float* __restrict__ bv,
                                              unsigned short* __restrict__ Q,
                                              unsigned short* __restrict__ K,
                                              unsigned short* __restrict__ Vt,
                                              unsigned short* __restrict__ IK,
                                              unsigned short* __restrict__ IVt) {
  __shared__ unsigned short Asm[2][128 * 32];
  __shared__ unsigned short Bsm[2][128 * 32];
  const int tid = threadIdx.x, lane = tid & 63, w = tid >> 6;
  const int lg = lane >> 4, lc = lane & 15;
  const int m0 = blockIdx.y * 128, n0 = blockIdx.x * 128;
  const int wm = (w >> 1) * 64, wn = (w & 1) * 64;

  f32x4 acc[4][4];
  #pragma unroll
  for (int i = 0; i < 4; ++i)
    #pragma unroll
    for (int j = 0; j < 4; ++j) acc[i][j] = (f32x4){0.f, 0.f, 0.f, 0.f};

  // stage k-tile kt into buffer bi
  #define STAGE(bi, kt)                                                          \
    {                                                                            \
      const int k0_ = (kt) * 32;                                                 \
      _Pragma("unroll")                                                          \
      for (int j_ = 0; j_ < 2; ++j_) {                                           \
        int c_ = w * 128 + j_ * 64 + lane;                                       \
        int r_ = c_ >> 2, cc_ = c_ & 3;                                          \
        gload_lds16(X + (size_t)(m0 + r_) * 1024 + k0_ + cc_ * 8,                \
                    &Asm[bi][(w * 128 + j_ * 64) * 8]);                          \
        gload_lds16(Wt + (size_t)(n0 + r_) * 1024 + k0_ + cc_ * 8,               \
                    &Bsm[bi][(w * 128 + j_ * 64) * 8]);                          \
      }                                                                          \
    }

  STAGE(0, 0);
  int cur = 0;
  for (int kt = 0; kt < 32; ++kt) {
    __syncthreads();            // drains staging of buf cur, and prior reads
    if (kt + 1 < 32) STAGE(cur ^ 1, kt + 1);
    const unsigned short* A = Asm[cur];
    const unsigned short* B = Bsm[cur];
    bf16x8 af[4], bfr[4];
    #pragma unroll
    for (int i = 0; i < 4; ++i)
      af[i] = *(const bf16x8*)(A + (wm + i * 16 + lc) * 32 + lg * 8);
    #pragma unroll
    for (int j = 0; j < 4; ++j)
      bfr[j] = *(const bf16x8*)(B + (wn + j * 16 + lc) * 32 + lg * 8);
    #pragma unroll
    for (int i = 0; i < 4; ++i)
      #pragma unroll
      for (int j = 0; j < 4; ++j)
        acc[i][j] = mfma16(af[i], bfr[j], acc[i][j]);
    cur ^= 1;
  }
  #undef STAGE

  // epilogue
  #pragma unroll
  for (int j = 0; j < 4; ++j) {
    const int gn = n0 + wn + j * 16 + lc;
    const int which = gn >> 10, nn = gn & 1023;
    const int hh = nn >> 6, dd = nn & 63;
    const float bias = (which == 0 ? bq : (which == 1 ? bk : bv))[nn];
    #pragma unroll
    for (int i = 0; i < 4; ++i) {
      #pragma unroll
      for (int ii = 0; ii < 4; ++ii) {
        const int gm = m0 + wm + i * 16 + lg * 4 + ii;
        const unsigned short o = f2bf(acc[i][j][ii] + bias);
        if (gm < 4096) {
          const int bb = gm >> 9, ss = gm & 511;
          if (which == 0)      Q[(((size_t)(bb * NH + hh) * 512 + ss) << 6) + dd] = o;
          else if (which == 1) K[(((size_t)(bb * NH + hh) * 512 + ss) << 6) + dd] = o;
          else                 Vt[((size_t)(bb * NH + hh) * 64 + dd) * 512 + ss] = o;
        } else {
          const int mi = gm - 4096, bb = mi >> 6, si = mi & 63;
          if (which == 1)      IK[((size_t)(bb * NH + hh) * 64 + si) * 64 + dd] = o;
          else if (which == 2) IVt[((size_t)(bb * NH + hh) * 64 + dd) * 64 + si] = o;
        }
      }
    }
  }
}

// ---------------- fused attention with relative-position bias ----------------
// grid: (8 q-tiles, 16 heads, 8 batch), 256 threads (4 waves); wave w owns q-rows [16w,16w+16)
__global__ __launch_bounds__(256, 2) void k_attn(const unsigned short* __restrict__ Qg,
                                                 const unsigned short* __restrict__ Kg,
                                                 const unsigned short* __restrict__ Vtg,
                                                 const unsigned short* __restrict__ IKg,
                                                 const unsigned short* __restrict__ IVtg,
                                                 const unsigned short* __restrict__ Eg,
                                                 const float* __restrict__ mask,
                                                 const float* __restrict__ imask,
                                                 const float* __restrict__ gate,
                                                 float* __restrict__ out) {
  const int lt = blockIdx.x, h = blockIdx.y, b = blockIdx.z;
  const int l0 = lt * 64;
  const int tid = threadIdx.x;
  const int lane = tid & 63, w = tid >> 6;
  const int lg = lane >> 4, lc = lane & 15;
  const int bh = b * NH + h;

  __shared__ unsigned short Qs[64][72], Ks[64][72], Vts[64][72], Ps[64][72];
  __shared__ unsigned short qds[64][136], kds[64][136];

  // stage Q tile (rows l0..l0+63)
  {
    const unsigned short* g = Qg + ((size_t)(bh * 512 + l0)) * 64;
    #pragma unroll
    for (int q = 0; q < 2; ++q) {
      int ch = tid + q * 256, r = ch >> 3, c = ch & 7;
      *(uint4*)(&Qs[r][c * 8]) = *(const uint4*)(g + r * 64 + c * 8);
    }
  }

  f32x4 oacc[4];
  #pragma unroll
  for (int i = 0; i < 4; ++i) oacc[i] = (f32x4){0.f, 0.f, 0.f, 0.f};
  float mrun[4], lrun[4];
  #pragma unroll
  for (int i = 0; i < 4; ++i) { mrun[i] = -3.0e38f; lrun[i] = 0.f; }
  const float scale = 0.125f;

  for (int rt = 0; rt < 8; ++rt) {
    const int r0 = rt * 64;
    {
      const unsigned short* gk = Kg + ((size_t)(bh * 512 + r0)) * 64;
      const unsigned short* gv = Vtg + ((size_t)bh * 64) * 512 + r0;
      #pragma unroll
      for (int q = 0; q < 2; ++q) {
        int ch = tid + q * 256, r = ch >> 3, c = ch & 7;
        *(uint4*)(&Ks[r][c * 8])  = *(const uint4*)(gk + r * 64 + c * 8);
        *(uint4*)(&Vts[r][c * 8]) = *(const uint4*)(gv + (size_t)r * 512 + c * 8);
      }
    }
    __syncthreads();

    // ---- qd/kd tile GEMMs against E slice; u = li - ri + 63, p = p0 + u ----
    const int p0 = l0 - r0 + 448;
    bf16x8 eb[2][2];
    #pragma unroll
    for (int ns = 0; ns < 2; ++ns) {
      const int u = (2 * w + ns) * 16 + lc;
      const unsigned short* ep = Eg + (size_t)(p0 + u) * 64 + lg * 8;
      eb[ns][0] = *(const bf16x8*)(ep);
      eb[ns][1] = *(const bf16x8*)(ep + 32);
    }
    {
      f32x4 da[4][2];
      #pragma unroll
      for (int ms = 0; ms < 4; ++ms) { da[ms][0] = (f32x4){0,0,0,0}; da[ms][1] = (f32x4){0,0,0,0}; }
      #pragma unroll
      for (int kc = 0; kc < 2; ++kc)
        #pragma unroll
        for (int ms = 0; ms < 4; ++ms) {
          bf16x8 a = *(const bf16x8*)(&Qs[ms * 16 + lc][kc * 32 + lg * 8]);
          da[ms][0] = mfma16(a, eb[0][kc], da[ms][0]);
          da[ms][1] = mfma16(a, eb[1][kc], da[ms][1]);
        }
      #pragma unroll
      for (int ms = 0; ms < 4; ++ms)
        #pragma unroll
        for (int ns = 0; ns < 2; ++ns)
          #pragma unroll
          for (int i = 0; i < 4; ++i)
            qds[ms * 16 + lg * 4 + i][(2 * w + ns) * 16 + lc] = f2bf(da[ms][ns][i]);
    }
    {
      f32x4 da[4][2];
      #pragma unroll
      for (int ms = 0; ms < 4; ++ms) { da[ms][0] = (f32x4){0,0,0,0}; da[ms][1] = (f32x4){0,0,0,0}; }
      #pragma unroll
      for (int kc = 0; kc < 2; ++kc)
        #pragma unroll
        for (int ms = 0; ms < 4; ++ms) {
          bf16x8 a = *(const bf16x8*)(&Ks[ms * 16 + lc][kc * 32 + lg * 8]);
          da[ms][0] = mfma16(a, eb[0][kc], da[ms][0]);
          da[ms][1] = mfma16(a, eb[1][kc], da[ms][1]);
        }
      #pragma unroll
      for (int ms = 0; ms < 4; ++ms)
        #pragma unroll
        for (int ns = 0; ns < 2; ++ns)
          #pragma unroll
          for (int i = 0; i < 4; ++i)
            kds[ms * 16 + lg * 4 + i][(2 * w + ns) * 16 + lc] = f2bf(da[ms][ns][i]);
    }
    __syncthreads();

    // ---- S = Q.K^T (+ gathered bias) ----
    f32x4 sacc[4];
    #pragma unroll
    for (int ns = 0; ns < 4; ++ns) sacc[ns] = (f32x4){0.f, 0.f, 0.f, 0.f};
    #pragma unroll
    for (int kc = 0; kc < 2; ++kc) {
      bf16x8 qa = *(const bf16x8*)(&Qs[w * 16 + lc][kc * 32 + lg * 8]);
      #pragma unroll
      for (int ns = 0; ns < 4; ++ns) {
        bf16x8 kb = *(const bf16x8*)(&Ks[ns * 16 + lc][kc * 32 + lg * 8]);
        sacc[ns] = mfma16(qa, kb, sacc[ns]);
      }
    }
    float sv[4][4];
    #pragma unroll
    for (int ns = 0; ns < 4; ++ns) {
      const float mk = mask[b * SEQ + r0 + ns * 16 + lc];
      #pragma unroll
      for (int i = 0; i < 4; ++i) {
        const int li = w * 16 + lg * 4 + i;
        const int ri = ns * 16 + lc;
        const int u = li - ri + 63;
        float x = sacc[ns][i] + bf2f(qds[li][u]) + bf2f(kds[ri][u]);
        sv[ns][i] = x * scale + mk;
      }
    }
    // ---- online softmax (rows live in 16-lane groups) ----
    #pragma unroll
    for (int i = 0; i < 4; ++i) {
      float mt = fmaxf(fmaxf(sv[0][i], sv[1][i]), fmaxf(sv[2][i], sv[3][i]));
      #pragma unroll
      for (int m = 1; m <= 8; m <<= 1) mt = fmaxf(mt, __shfl_xor(mt, m));
      const float mnew = fmaxf(mrun[i], mt);
      const float fr = __expf(mrun[i] - mnew);
      mrun[i] = mnew;
      float ps = 0.f;
      #pragma unroll
      for (int ns = 0; ns < 4; ++ns) { float p = __expf(sv[ns][i] - mnew); sv[ns][i] = p; ps += p; }
      #pragma unroll
      for (int m = 1; m <= 8; m <<= 1) ps += __shfl_xor(ps, m);
      lrun[i] = lrun[i] * fr + ps;
      #pragma unroll
      for (int ds = 0; ds < 4; ++ds) oacc[ds][i] *= fr;
    }
    #pragma unroll
    for (int ns = 0; ns < 4; ++ns)
      #pragma unroll
      for (int i = 0; i < 4; ++i)
        Ps[w * 16 + lg * 4 + i][ns * 16 + lc] = f2bf(sv[ns][i]);
    // ---- PV (intra-wave: wave reads only its own P rows) ----
    #pragma unroll
    for (int kc = 0; kc < 2; ++kc) {
      bf16x8 pa = *(const bf16x8*)(&Ps[w * 16 + lc][kc * 32 + lg * 8]);
      #pragma unroll
      for (int ds = 0; ds < 4; ++ds) {
        bf16x8 vb = *(const bf16x8*)(&Vts[ds * 16 + lc][kc * 32 + lg * 8]);
        oacc[ds] = mfma16(pa, vb, oacc[ds]);
      }
    }
    __syncthreads();
  }

  // ---- instruct branch (one 64-col tile, separate softmax) ----
  {
    const unsigned short* gk = IKg + (size_t)bh * 4096;
    const unsigned short* gv = IVtg + (size_t)bh * 4096;
    #pragma unroll
    for (int q = 0; q < 2; ++q) {
      int ch = tid + q * 256, r = ch >> 3, c = ch & 7;
      *(uint4*)(&Ks[r][c * 8])  = *(const uint4*)(gk + r * 64 + c * 8);
      *(uint4*)(&Vts[r][c * 8]) = *(const uint4*)(gv + r * 64 + c * 8);
    }
    __syncthreads();
    f32x4 sacc[4];
    #pragma unroll
    for (int ns = 0; ns < 4; ++ns) sacc[ns] = (f32x4){0.f, 0.f, 0.f, 0.f};
    #pragma unroll
    for (int kc = 0; kc < 2; ++kc) {
      bf16x8 qa = *(const bf16x8*)(&Qs[w * 16 + lc][kc * 32 + lg * 8]);
      #pragma unroll
      for (int ns = 0; ns < 4; ++ns) {
        bf16x8 kb = *(const bf16x8*)(&Ks[ns * 16 + lc][kc * 32 + lg * 8]);
        sacc[ns] = mfma16(qa, kb, sacc[ns]);
      }
    }
    float sv[4][4], isum[4];
    #pragma unroll
    for (int ns = 0; ns < 4; ++ns) {
      const float mk = imask[b * SIN + ns * 16 + lc];
      #pragma unroll
      for (int i = 0; i < 4; ++i) sv[ns][i] = sacc[ns][i] * scale + mk;
    }
    #pragma unroll
    for (int i = 0; i < 4; ++i) {
      float mt = fmaxf(fmaxf(sv[0][i], sv[1][i]), fmaxf(sv[2][i], sv[3][i]));
      #pragma unroll
      for (int m = 1; m <= 8; m <<= 1) mt = fmaxf(mt, __shfl_xor(mt, m));
      float ps = 0.f;
      #pragma unroll
      for (int ns = 0; ns < 4; ++ns) { float p = __expf(sv[ns][i] - mt); sv[ns][i] = p; ps += p; }
      #pragma unroll
      for (int m = 1; m <= 8; m <<= 1) ps += __shfl_xor(ps, m);
      isum[i] = ps;
    }
    #pragma unroll
    for (int ns = 0; ns < 4; ++ns)
      #pragma unroll
      for (int i = 0; i < 4; ++i)
        Ps[w * 16 + lg * 4 + i][ns * 16 + lc] = f2bf(sv[ns][i]);
    f32x4 iacc[4];
    #pragma unroll
    for (int ds = 0; ds < 4; ++ds) iacc[ds] = (f32x4){0.f, 0.f, 0.f, 0.f};
    #pragma unroll
    for (int kc = 0; kc < 2; ++kc) {
      bf16x8 pa = *(const bf16x8*)(&Ps[w * 16 + lc][kc * 32 + lg * 8]);
      #pragma unroll
      for (int ds = 0; ds < 4; ++ds) {
        bf16x8 vb = *(const bf16x8*)(&Vts[ds * 16 + lc][kc * 32 + lg * 8]);
        iacc[ds] = mfma16(pa, vb, iacc[ds]);
      }
    }
    const float tg = tanhf(gate[h]);
    #pragma unroll
    for (int ds = 0; ds < 4; ++ds)
      #pragma unroll
      for (int i = 0; i < 4; ++i) {
        const int li = w * 16 + lg * 4 + i;
        const float val = oacc[ds][i] / lrun[i] + tg * (iacc[ds][i] / isum[i]);
        out[(size_t)(b * SEQ + l0 + li) * 1024 + h * 64 + ds * 16 + lc] = val;
      }
  }
}

// ---------------- launch ----------------

extern "C" void kernel_launch(void* const* d_in, const int* in_sizes, int n_in,
                              void* d_out, int out_size, void* d_ws, size_t ws_size,
                              hipStream_t stream) {
  (void)in_sizes; (void)n_in; (void)out_size; (void)ws_size;
  const float* hs    = (const float*)d_in[0];
  const float* ihs   = (const float*)d_in[1];
  const float* mask  = (const float*)d_in[2];
  const float* imask = (const float*)d_in[3];
  const float* Wq    = (const float*)d_in[4];
  const float* bq    = (const float*)d_in[5];
  const float* Wk    = (const float*)d_in[6];
  const float* bk    = (const float*)d_in[7];
  const float* Wv    = (const float*)d_in[8];
  const float* bv    = (const float*)d_in[9];
  const float* de    = (const float*)d_in[10];
  const float* gate  = (const float*)d_in[11];
  float* out = (float*)d_out;

  char* ws = (char*)d_ws;
  size_t off = 0;
  auto alloc = [&](size_t bytes) -> void* {
    void* p = ws + off;
    off += (bytes + 255) & ~(size_t)255;
    return p;
  };
  unsigned short* X    = (unsigned short*)alloc((size_t)4608 * 1024 * 2);
  unsigned short* Wt   = (unsigned short*)alloc((size_t)3072 * 1024 * 2);
  unsigned short* E    = (unsigned short*)alloc((size_t)1024 * 64 * 2);
  unsigned short* Qb   = (unsigned short*)alloc((size_t)8 * 16 * 512 * 64 * 2);
  unsigned short* Kb   = (unsigned short*)alloc((size_t)8 * 16 * 512 * 64 * 2);
  unsigned short* Vtb  = (unsigned short*)alloc((size_t)8 * 16 * 64 * 512 * 2);
  unsigned short* IKb  = (unsigned short*)alloc((size_t)8 * 16 * 64 * 64 * 2);
  unsigned short* IVtb = (unsigned short*)alloc((size_t)8 * 16 * 64 * 64 * 2);

  k_convert_x<<<4608, 256, 0, stream>>>(hs, ihs, X);
  k_convert_w<<<dim3(16, 16, 3), 256, 0, stream>>>(Wq, Wk, Wv, Wt);
  k_convert_e<<<64, 256, 0, stream>>>(de, E);
  k_gemm<<<dim3(24, 36), 256, 0, stream>>>(X, Wt, bq, bk, bv, Qb, Kb, Vtb, IKb, IVtb);
  k_attn<<<dim3(8, 16, 8), 256, 0, stream>>>(Qb, Kb, Vtb, IKb, IVtb, E, mask, imask, gate, out);
}